// Round 14
// baseline (196.535 us; speedup 1.0000x reference)
//
#include <hip/hip_runtime.h>
#include <hip/hip_bf16.h>
#include <cstdint>
#include <cstddef>

#define D_MODEL 1024
#define NHEADS 16
#define HD 64
#define NB 2
#define SL 2048
#define SEQ (NB*SL)      // 4096
#define NQKV (3*D_MODEL) // 3072

typedef __attribute__((ext_vector_type(8))) short short8;
typedef __attribute__((ext_vector_type(4))) float floatx4;
typedef __attribute__((ext_vector_type(16))) float f32x16;
typedef unsigned short u16;

__device__ __forceinline__ u16 f2bf(float f) {
    union { float f; uint32_t u; } v; v.f = f;
    return (u16)((v.u + 0x7fffu + ((v.u >> 16) & 1u)) >> 16);
}

__device__ __forceinline__ uint32_t cvt_pk_bf16(float lo, float hi) {
    uint32_t r;
    asm("v_cvt_pk_bf16_f32 %0, %1, %2" : "=v"(r) : "v"(lo), "v"(hi));
    return r;
}

// swaps a.hi-half with b.lo-half. NOTE (R10-R12): only safe with two GENUINELY
// DISTINCT values (PV_SUB). Self-join failed twice — use __shfl_xor for that.
__device__ __forceinline__ void pl32swap(uint32_t &a, uint32_t &b) {
    asm("v_permlane32_swap_b32 %0, %1" : "+v"(a), "+v"(b));
}

// raw v_exp_f32: computes 2^x
__device__ __forceinline__ float exp2f_fast(float x) {
    float r; asm("v_exp_f32 %0, %1" : "=v"(r) : "v"(x)); return r;
}

__device__ __forceinline__ float m3f(float a, float b, float c) {
    return fmaxf(fmaxf(a, b), c);   // clang fuses to v_max3_f32
}

__device__ __forceinline__ float vmax16(const f32x16& v) {
    float a0 = m3f(v[0], v[1], v[2]);
    float a1 = m3f(v[3], v[4], v[5]);
    float a2 = m3f(v[6], v[7], v[8]);
    float a3 = m3f(v[9], v[10], v[11]);
    float a4 = m3f(v[12], v[13], v[14]);
    return fmaxf(m3f(a0, a1, v[15]), m3f(a2, a3, a4));
}

__device__ __forceinline__ f32x16 zero16() {
    f32x16 z;
    #pragma unroll
    for (int i = 0; i < 16; i++) z[i] = 0.f;
    return z;
}

#define GLDS(gsrc, ldst) __builtin_amdgcn_global_load_lds( \
    (const __attribute__((address_space(1))) void*)(gsrc), \
    (__attribute__((address_space(3))) void*)(ldst), 16, 0, 0)

// ---------------- fp32 -> bf16 convert, all three tensors in one launch ----------------
__global__ __launch_bounds__(256) void cvt_all(const float* __restrict__ x,
                                               const float* __restrict__ w1,
                                               const float* __restrict__ w2,
                                               u16* __restrict__ xb,
                                               u16* __restrict__ w1b,
                                               u16* __restrict__ w2b) {
    int i = blockIdx.x * 256 + threadIdx.x;
    const float4* src; ushort4* dst; int j;
    if (i < 1048576)      { src = (const float4*)x;  dst = (ushort4*)xb;  j = i; }
    else if (i < 1835008) { src = (const float4*)w1; dst = (ushort4*)w1b; j = i - 1048576; }
    else                  { src = (const float4*)w2; dst = (ushort4*)w2b; j = i - 1835008; }
    float4 f = src[j];
    ushort4 o;
    o.x = f2bf(f.x); o.y = f2bf(f.y); o.z = f2bf(f.z); o.w = f2bf(f.w);
    dst[j] = o;
}

// ---------------- double-buffered 128Mx64N GEMM mainloop (proj): C = A * B^T ----------------
__device__ __forceinline__ void gemm128x64_dbuf(const u16* __restrict__ A,
                                                const u16* __restrict__ B,
                                                int mbase, int nbase, int K,
                                                u16* Alds, u16* Blds,
                                                floatx4 acc[4][2]) {
    const int tid = threadIdx.x;
    const int lane = tid & 63;
    const int l15 = lane & 15, quad = lane >> 4;
    const int wave = tid >> 6;
    const int wr = wave >> 1, wc = wave & 1;
    #pragma unroll
    for (int i = 0; i < 4; i++)
        #pragma unroll
        for (int j = 0; j < 2; j++)
            acc[i][j] = (floatx4){0.f, 0.f, 0.f, 0.f};

    const int r0 = tid >> 2, kg0 = (tid & 3) * 8;
    const u16* Arow0 = A + (size_t)(mbase + r0) * K + kg0;
    const u16* Arow1 = A + (size_t)(mbase + r0 + 64) * K + kg0;
    const u16* Brow0 = B + (size_t)(nbase + r0) * K + kg0;

    GLDS(Arow0, Alds + tid * 8);
    GLDS(Arow1, Alds + (256 + tid) * 8);
    GLDS(Brow0, Blds + tid * 8);
    __syncthreads();

    const int NT = K >> 5;
    for (int t = 0; t < NT; t++) {
        const int cur = t & 1;
        if (t + 1 < NT) {
            const int k0 = (t + 1) << 5;
            u16* Ad = Alds + (cur ^ 1) * 4096;
            u16* Bd = Blds + (cur ^ 1) * 2048;
            GLDS(Arow0 + k0, Ad + tid * 8);
            GLDS(Arow1 + k0, Ad + (256 + tid) * 8);
            GLDS(Brow0 + k0, Bd + tid * 8);
        }
        const u16* Ac = Alds + cur * 4096;
        const u16* Bc = Blds + cur * 2048;
        short8 af[4], bf[2];
        #pragma unroll
        for (int i = 0; i < 4; i++)
            af[i] = *(const short8*)(Ac + (wr * 64 + i * 16 + l15) * 32 + quad * 8);
        #pragma unroll
        for (int j = 0; j < 2; j++)
            bf[j] = *(const short8*)(Bc + (wc * 32 + j * 16 + l15) * 32 + quad * 8);
        #pragma unroll
        for (int i = 0; i < 4; i++)
            #pragma unroll
            for (int j = 0; j < 2; j++)
                acc[i][j] = __builtin_amdgcn_mfma_f32_16x16x32_bf16(af[i], bf[j], acc[i][j], 0, 0, 0);
        __syncthreads();   // drains vmcnt (tile t+1 staged) + WAR guard
    }
}

// ---------------- QKV GEMM v2: 256x256 tile, BK=64, 8 waves, 4-phase K-steps ----------------
// (R6 kernel, acquitted: its only "failure" was an infra flake — R11/R12 proved
// container-failed-twice != kernel bug. Re-audited: fragment algebra, 6 uniform
// barriers/KSTEP, WAR rotation, vmcnt=8-own-loads accounting all check.)
// Fragment-major LDS via pre-permuted per-lane GLOBAL source (rule #21: LDS dest
// linear). Per K-step: 4 phases {ds_read subtile | stage -> barrier -> setprio(1)
// 16 MFMA setprio(0) -> barrier}; ONE vmcnt(0) per 64 MFMA (vs 16 in 2-phase).
// A-tile chunk s (16B): mm=s>>7, kk=(s>>6)&1, qs=(s>>4)&3, ls=s&15 holds
//   A[row=mm*16+ls][k=kk*32+qs*8 ..+8];  B-tile identical on N.

#define QMFMA(MOFF, NOFF) \
    _Pragma("unroll") for (int mf_ = 0; mf_ < 4; mf_++) \
    _Pragma("unroll") for (int nf_ = 0; nf_ < 2; nf_++) \
    _Pragma("unroll") for (int kk_ = 0; kk_ < 2; kk_++) \
        acc[(MOFF)+mf_][(NOFF)+nf_] = __builtin_amdgcn_mfma_f32_16x16x32_bf16( \
            af[mf_][kk_], bf[(NOFF)+nf_][kk_], acc[(MOFF)+mf_][(NOFF)+nf_], 0, 0, 0);

#define KSTEP(CA, CB, NA, NB_, KCOL, DOSTAGE) {                                  \
    _Pragma("unroll") for (int mf_ = 0; mf_ < 4; mf_++)                          \
      _Pragma("unroll") for (int kk_ = 0; kk_ < 2; kk_++)                        \
        af[mf_][kk_] = *(const short8*)((CA) + ArdB + (mf_*2+kk_)*512);          \
    _Pragma("unroll") for (int nf_ = 0; nf_ < 2; nf_++)                          \
      _Pragma("unroll") for (int kk_ = 0; kk_ < 2; kk_++)                        \
        bf[nf_][kk_] = *(const short8*)((CB) + BrdB + (nf_*2+kk_)*512);          \
    if (DOSTAGE) {                                                               \
      _Pragma("unroll") for (int r_ = 0; r_ < 4; r_++)                           \
        GLDS(srcA[r_] + (KCOL), (NA) + dOff[r_]);                                \
    }                                                                            \
    __builtin_amdgcn_s_barrier();                                                \
    __builtin_amdgcn_s_setprio(1);                                               \
    QMFMA(0, 0)                                                                  \
    __builtin_amdgcn_s_setprio(0);                                               \
    __builtin_amdgcn_s_barrier();                                                \
    _Pragma("unroll") for (int nf_ = 0; nf_ < 2; nf_++)                          \
      _Pragma("unroll") for (int kk_ = 0; kk_ < 2; kk_++)                        \
        bf[2+nf_][kk_] = *(const short8*)((CB) + BrdB + ((2+nf_)*2+kk_)*512);    \
    if (DOSTAGE) {                                                               \
      _Pragma("unroll") for (int r_ = 0; r_ < 4; r_++)                           \
        GLDS(srcB[r_] + (KCOL), (NB_) + dOff[r_]);                               \
    }                                                                            \
    __builtin_amdgcn_s_barrier();                                                \
    __builtin_amdgcn_s_setprio(1);                                               \
    QMFMA(0, 2)                                                                  \
    __builtin_amdgcn_s_setprio(0);                                               \
    __builtin_amdgcn_s_barrier();                                                \
    _Pragma("unroll") for (int mf_ = 0; mf_ < 4; mf_++)                          \
      _Pragma("unroll") for (int kk_ = 0; kk_ < 2; kk_++)                        \
        af[mf_][kk_] = *(const short8*)((CA) + ArdB + ((4+mf_)*2+kk_)*512);      \
    __builtin_amdgcn_s_barrier();                                                \
    __builtin_amdgcn_s_setprio(1);                                               \
    QMFMA(4, 2)                                                                  \
    __builtin_amdgcn_s_setprio(0);                                               \
    __builtin_amdgcn_s_barrier();                                                \
    __builtin_amdgcn_s_setprio(1);                                               \
    QMFMA(4, 0)                                                                  \
    __builtin_amdgcn_s_setprio(0);                                               \
    asm volatile("s_waitcnt vmcnt(0)" ::: "memory");                             \
    __builtin_amdgcn_s_barrier();                                                \
}

__global__ __launch_bounds__(512, 2) void qkv_gemm(const u16* __restrict__ xb,
                                                   const u16* __restrict__ wb,
                                                   const float* __restrict__ bias,
                                                   u16* __restrict__ Qo, u16* __restrict__ Ko,
                                                   u16* __restrict__ Vt) {
    __shared__ __align__(16) u16 smem[65536];   // A0|A1|B0|B1, 32 KB each (128 KB)
    const int tid = threadIdx.x;
    const int lane = tid & 63;
    const int wave = tid >> 6;               // 0..7, 2M x 4N
    const int wr = wave >> 2, wc = wave & 3;
    const int l15 = lane & 15, quad = lane >> 4;
    const int mbase = blockIdx.y * 256;
    const int nbase = blockIdx.x * 256;

    // per-thread staging descriptors: round r stages chunk s = r*512 + tid
    const u16* srcA[4]; const u16* srcB[4]; int dOff[4];
    #pragma unroll
    for (int r = 0; r < 4; r++) {
        int s = r * 512 + tid;
        int mm = s >> 7, kk = (s >> 6) & 1, qs = (s >> 4) & 3, ls = s & 15;
        srcA[r] = xb + (size_t)(mbase + mm * 16 + ls) * 1024 + kk * 32 + qs * 8;
        srcB[r] = wb + (size_t)(nbase + mm * 16 + ls) * 1024 + kk * 32 + qs * 8;
        dOff[r] = s * 8;
    }
    u16* const A0 = smem;
    u16* const A1 = smem + 16384;
    u16* const B0 = smem + 32768;
    u16* const B1 = smem + 49152;

    // ds_read bases (u16): frag (mf,kk) at ArdB + (mf*2+kk)*512 (mf local to wr-half)
    const int ArdB = wr * 8192 + lane * 8;
    const int BrdB = wc * 4096 + lane * 8;

    floatx4 acc[8][4];
    #pragma unroll
    for (int i = 0; i < 8; i++)
        #pragma unroll
        for (int j = 0; j < 4; j++)
            acc[i][j] = (floatx4){0.f, 0.f, 0.f, 0.f};
    short8 af[4][2], bf[4][2];

    // prologue: stage K-step 0 into buf0
    #pragma unroll
    for (int r = 0; r < 4; r++) GLDS(srcA[r], A0 + dOff[r]);
    #pragma unroll
    for (int r = 0; r < 4; r++) GLDS(srcB[r], B0 + dOff[r]);
    asm volatile("s_waitcnt vmcnt(0)" ::: "memory");
    __builtin_amdgcn_s_barrier();

    #pragma unroll 1
    for (int tt = 0; tt < 8; tt++) {
        const int kc1 = (tt * 2 + 1) * 64;
        const int kc2 = (tt * 2 + 2) * 64;
        KSTEP(A0, B0, A1, B1, kc1, true)
        KSTEP(A1, B1, A0, B0, kc2, (tt < 7))
    }

    // epilogue: m = mbase + wr*128 + mf*16 + quad*4 + r ; n = nbase + wc*64 + nf*16 + l15
    const int which = nbase >> 10;   // uniform per block (256 | 1024 boundaries)
    #pragma unroll
    for (int nf = 0; nf < 4; nf++) {
        int n = nbase + wc * 64 + nf * 16 + l15;
        float bv = bias[n];
        int within = n & 1023;
        int h = within >> 6, d = within & 63;
        #pragma unroll
        for (int mf = 0; mf < 8; mf++) {
            int m0 = mbase + wr * 128 + mf * 16 + quad * 4;
            int b = m0 >> 11;
            int bh = b * NHEADS + h;
            if (which == 2) {
                int l0 = m0 & 2047;
                int slot = ((l0 >> 5) & 1) * 256 + ((l0 >> 4) & 1) * 128 + (d >> 5) * 64 + ((l0 >> 3) & 1) * 32 + (d & 31);
                ushort4 pk;
                pk.x = f2bf(acc[mf][nf][0] + bv); pk.y = f2bf(acc[mf][nf][1] + bv);
                pk.z = f2bf(acc[mf][nf][2] + bv); pk.w = f2bf(acc[mf][nf][3] + bv);
                *(ushort4*)(Vt + (size_t)bh * (SL * HD) + (size_t)(l0 >> 6) * 4096 + slot * 8 + (l0 & 7)) = pk;
            } else {
                #pragma unroll
                for (int r = 0; r < 4; r++) {
                    int m = m0 + r;
                    int l = m & 2047;
                    float v = acc[mf][nf][r] + bv;
                    if (which == 0) {
                        // SCALE * log2(e) folded -> flash works in exp2 domain
                        Qo[((size_t)bh * SL + l) * HD + d] = f2bf(v * 0.18033688f);
                    } else {
                        int slot = ((l >> 5) & 1) * 256 + (d >> 4) * 64 + ((d >> 3) & 1) * 32 + (l & 31);
                        Ko[(size_t)bh * (SL * HD) + (size_t)(l >> 6) * 4096 + slot * 8 + (d & 7)] = f2bf(v);
                    }
                }
            }
        }
    }
}

// ---------------- Flash attention v8: in-block KV-split + DEFERRED l_i join ----------------
__global__ __launch_bounds__(512, 4) void flash_kernel(const u16* __restrict__ Q,
                                                       const u16* __restrict__ K,
                                                       const u16* __restrict__ V,
                                                       u16* __restrict__ AO) {
    __shared__ __align__(16) u16 smem[32768];   // [half][K dbuf 8192 u16 | V dbuf 8192 u16]
    const int tid = threadIdx.x;
    const int lane = tid & 63;
    const int wave = tid >> 6;          // 0..7
    const int qc = wave & 3;            // q-chunk within block
    const int kvh = wave >> 2;          // KV half
    const int tl = tid & 255;           // thread index within half-group
    const int hi = lane >> 5;
    const int l31 = lane & 31;
    const int lane8 = lane * 8;

    const int bid = (int)blockIdx.x;
    const int swz = (bid & 7) * 64 + (bid >> 3);
    const int bh = swz >> 4;
    const int qb = swz & 15;
    const int b = bh >> 4, hd = bh & 15;
    const int qbase = qb * 128 + qc * 32;

    const u16* Qp = Q + (size_t)bh * SL * HD;
    const u16* Kg = K + (size_t)bh * (SL * HD) + (size_t)kvh * 16 * 4096;
    const u16* Vg = V + (size_t)bh * (SL * HD) + (size_t)kvh * 16 * 4096;

    u16* Kb_ = smem + kvh * 16384;
    u16* Vb_ = smem + kvh * 16384 + 8192;

    short8 qf[4];
    #pragma unroll
    for (int c = 0; c < 4; c++)
        qf[c] = *(const short8*)(Qp + (size_t)(qbase + l31) * HD + c * 16 + hi * 8);

    f32x16 accO0 = zero16(), accO1 = zero16();
    float m_i = -__builtin_inff();
    float l_i = 0.f;    // per-lane HALF-row partial; joined once after the loop

    GLDS(Kg + tl * 8,         Kb_ + tl * 8);
    GLDS(Kg + (256 + tl) * 8, Kb_ + (256 + tl) * 8);
    GLDS(Vg + tl * 8,         Vb_ + tl * 8);
    GLDS(Vg + (256 + tl) * 8, Vb_ + (256 + tl) * 8);
    __syncthreads();

    union PW { uint32_t w[4]; short8 s8; };

    #pragma unroll 1
    for (int t = 0; t < 16; t++) {
        const int cur = t & 1;
        if (t + 1 < 16) {
            const u16* ks = Kg + (size_t)(t + 1) * 4096;
            const u16* vs = Vg + (size_t)(t + 1) * 4096;
            u16* kd = Kb_ + (cur ^ 1) * 4096;
            u16* vd = Vb_ + (cur ^ 1) * 4096;
            GLDS(ks + tl * 8,         kd + tl * 8);
            GLDS(ks + (256 + tl) * 8, kd + (256 + tl) * 8);
            GLDS(vs + tl * 8,         vd + tl * 8);
            GLDS(vs + (256 + tl) * 8, vd + (256 + tl) * 8);
        }
        const u16* Kt  = Kb_ + cur * 4096;
        const u16* Vt_ = Vb_ + cur * 4096;

        f32x16 sA = zero16(), sB = zero16();
        __builtin_amdgcn_s_setprio(1);
        #pragma unroll
        for (int c = 0; c < 4; c++) {
            short8 kf = *(const short8*)(Kt + c * 512 + lane8);
            sA = __builtin_amdgcn_mfma_f32_32x32x16_bf16(kf, qf[c], sA, 0, 0, 0);
        }
        #pragma unroll
        for (int c = 0; c < 4; c++) {
            short8 kf = *(const short8*)(Kt + 2048 + c * 512 + lane8);
            sB = __builtin_amdgcn_mfma_f32_32x32x16_bf16(kf, qf[c], sB, 0, 0, 0);
        }
        __builtin_amdgcn_s_setprio(0);

        float pmax = fmaxf(vmax16(sA), vmax16(sB));
        if (!__all(pmax - m_i <= 24.0f)) {
            float mo = m_i;
            float mn = fmaxf(mo, fmaxf(pmax, __shfl_xor(pmax, 32, 64)));  // pair-consistent m
            m_i = mn;
            float alpha = exp2f_fast(mo - mn);
            l_i *= alpha;
            #pragma unroll
            for (int e = 0; e < 16; e++) { accO0[e] *= alpha; accO1[e] *= alpha; }
        }
        #pragma unroll
        for (int e = 0; e < 16; e++) sA[e] = exp2f_fast(sA[e] - m_i);
        #pragma unroll
        for (int e = 0; e < 16; e++) sB[e] = exp2f_fast(sB[e] - m_i);
        float r0 = 0.f, r1 = 0.f, r2 = 0.f, r3 = 0.f;
        #pragma unroll
        for (int e = 0; e < 16; e += 4) {
            r0 += sA[e]; r1 += sA[e + 1]; r2 += sA[e + 2]; r3 += sA[e + 3];
        }
        #pragma unroll
        for (int e = 0; e < 16; e += 4) {
            r0 += sB[e]; r1 += sB[e + 1]; r2 += sB[e + 2]; r3 += sB[e + 3];
        }
        l_i += (r0 + r1) + (r2 + r3);   // half-row partial; NO per-tile join (v8)

#define PV_SUB(SV, OFF) { \
        uint32_t a0 = cvt_pk_bf16(SV[0], SV[1]);  uint32_t b0 = cvt_pk_bf16(SV[4], SV[5]);  pl32swap(a0, b0); \
        uint32_t a1 = cvt_pk_bf16(SV[2], SV[3]);  uint32_t b1 = cvt_pk_bf16(SV[6], SV[7]);  pl32swap(a1, b1); \
        PW f0; f0.w[0] = a0; f0.w[1] = a1; f0.w[2] = b0; f0.w[3] = b1; \
        accO0 = __builtin_amdgcn_mfma_f32_32x32x16_bf16(*(const short8*)(Vt_ + (OFF) + lane8),        f0.s8, accO0, 0, 0, 0); \
        accO1 = __builtin_amdgcn_mfma_f32_32x32x16_bf16(*(const short8*)(Vt_ + (OFF) + 512 + lane8),  f0.s8, accO1, 0, 0, 0); \
        uint32_t c0 = cvt_pk_bf16(SV[8], SV[9]);  uint32_t d0 = cvt_pk_bf16(SV[12], SV[13]); pl32swap(c0, d0); \
        uint32_t c1 = cvt_pk_bf16(SV[10], SV[11]); uint32_t d1 = cvt_pk_bf16(SV[14], SV[15]); pl32swap(c1, d1); \
        PW f1; f1.w[0] = c0; f1.w[1] = c1; f1.w[2] = d0; f1.w[3] = d1; \
        accO0 = __builtin_amdgcn_mfma_f32_32x32x16_bf16(*(const short8*)(Vt_ + (OFF) + 1024 + lane8),       f1.s8, accO0, 0, 0, 0); \
        accO1 = __builtin_amdgcn_mfma_f32_32x32x16_bf16(*(const short8*)(Vt_ + (OFF) + 1024 + 512 + lane8), f1.s8, accO1, 0, 0, 0); }

        __builtin_amdgcn_s_setprio(1);
        PV_SUB(sA, 0);
        PV_SUB(sB, 2048);
        __builtin_amdgcn_s_setprio(0);
#undef PV_SUB

        __syncthreads();
    }

    // ---- one-time lane-pair join of the deferred l_i partials (v8) ----
    l_i += __shfl_xor(l_i, 32, 64);

    // ---- cross-half combine through (now dead) staging LDS ----
    float* xch = (float*)smem;
    if (kvh) {
        float* p = xch + (qc * 64 + lane) * 35;
        #pragma unroll
        for (int e = 0; e < 16; e++) { p[e] = accO0[e]; p[16 + e] = accO1[e]; }
        p[32] = m_i; p[33] = l_i;
    }
    __syncthreads();
    if (!kvh) {
        const float* p = xch + (qc * 64 + lane) * 35;
        float mB = p[32], lB = p[33];
        float m = fmaxf(m_i, mB);
        float s0 = exp2f_fast(m_i - m);
        float s1 = exp2f_fast(mB - m);
        float inv = 1.f / (s0 * l_i + s1 * lB);
        const size_t rowbase = ((size_t)(b * SL + qbase + l31)) * D_MODEL + hd * HD;
        #pragma unroll
        for (int rg = 0; rg < 4; rg++) {
            ushort4 o0, o1;
            o0.x = f2bf((s0 * accO0[rg * 4 + 0] + s1 * p[rg * 4 + 0]) * inv);
            o0.y = f2bf((s0 * accO0[rg * 4 + 1] + s1 * p[rg * 4 + 1]) * inv);
            o0.z = f2bf((s0 * accO0[rg * 4 + 2] + s1 * p[rg * 4 + 2]) * inv);
            o0.w = f2bf((s0 * accO0[rg * 4 + 3] + s1 * p[rg * 4 + 3]) * inv);
            *(ushort4*)(AO + rowbase + rg * 8 + 4 * hi) = o0;
            o1.x = f2bf((s0 * accO1[rg * 4 + 0] + s1 * p[16 + rg * 4 + 0]) * inv);
            o1.y = f2bf((s0 * accO1[rg * 4 + 1] + s1 * p[16 + rg * 4 + 1]) * inv);
            o1.z = f2bf((s0 * accO1[rg * 4 + 2] + s1 * p[16 + rg * 4 + 2]) * inv);
            o1.w = f2bf((s0 * accO1[rg * 4 + 3] + s1 * p[16 + rg * 4 + 3]) * inv);
            *(ushort4*)(AO + rowbase + 32 + rg * 8 + 4 * hi) = o1;
        }
    }
}

// ---------------- Output projection: [4096,1024] x [1024,1024]^T + bias -> fp32 ----------------
__global__ __launch_bounds__(256) void proj_gemm(const u16* __restrict__ ab,
                                                 const u16* __restrict__ wb,
                                                 const float* __restrict__ bias,
                                                 float* __restrict__ out) {
    __shared__ __align__(16) u16 Alds[2 * 4096];
    __shared__ __align__(16) u16 Blds[2 * 2048];
    const int mbase = blockIdx.y * 128;
    const int nbase = blockIdx.x * 64;
    floatx4 acc[4][2];
    gemm128x64_dbuf(ab, wb, mbase, nbase, 1024, Alds, Blds, acc);
    const int lane = threadIdx.x & 63;
    const int wave = threadIdx.x >> 6;
    const int wr = wave >> 1, wc = wave & 1;
    const int l15 = lane & 15, quad = lane >> 4;
    #pragma unroll
    for (int j = 0; j < 2; j++) {
        int n = nbase + wc * 32 + j * 16 + l15;
        float bv = bias[n];
        #pragma unroll
        for (int i = 0; i < 4; i++) {
            #pragma unroll
            for (int r = 0; r < 4; r++) {
                int m = mbase + wr * 64 + i * 16 + quad * 4 + r;
                out[(size_t)m * D_MODEL + n] = acc[i][j][r] + bv;
            }
        }
    }
}

extern "C" void kernel_launch(void* const* d_in, const int* in_sizes, int n_in,
                              void* d_out, int out_size, void* d_ws, size_t ws_size,
                              hipStream_t stream) {
    const float* x      = (const float*)d_in[0];
    const float* qkv_w  = (const float*)d_in[1];
    const float* qkv_b  = (const float*)d_in[2];
    const float* proj_w = (const float*)d_in[3];
    const float* proj_b = (const float*)d_in[4];
    float* out = (float*)d_out;
    char* ws = (char*)d_ws;

    u16* xb    = (u16*)(ws);             // x bf16        [4096,1024]   8 MB
    u16* wqkv  = (u16*)(ws + 8388608);   // qkv_w bf16    [3072,1024]   6 MB
    u16* wproj = (u16*)(ws + 14680064);  // proj_w bf16   [1024,1024]   2 MB
    u16* Qb    = (u16*)(ws + 16777216);  // Q bf16 (pre-scaled, exp2 domain) 8 MB
    u16* Kb    = (u16*)(ws + 25165824);  // K bf16 fragment-major 8 MB
    u16* Vt    = (u16*)(ws + 33554432);  // V bf16 fragment-major 8 MB
    u16* AO    = (u16*)(ws);             // attn out bf16 ALIASES xb (lifetimes disjoint)

    cvt_all<<<8192, 256, 0, stream>>>(x, qkv_w, proj_w, xb, wqkv, wproj);
    qkv_gemm<<<dim3(NQKV / 256, SEQ / 256), 512, 0, stream>>>(xb, wqkv, qkv_b, Qb, Kb, Vt);
    flash_kernel<<<dim3(512), 512, 0, stream>>>(Qb, Kb, Vt, AO);
    proj_gemm<<<dim3(D_MODEL / 64, SEQ / 128), 256, 0, stream>>>(AO, wproj, proj_b, out);
}

// Round 15
// 193.978 us; speedup vs baseline: 1.0132x; 1.0132x over previous
//
#include <hip/hip_runtime.h>
#include <hip/hip_bf16.h>
#include <cstdint>
#include <cstddef>

#define D_MODEL 1024
#define NHEADS 16
#define HD 64
#define NB 2
#define SL 2048
#define SEQ (NB*SL)      // 4096
#define NQKV (3*D_MODEL) // 3072

typedef __attribute__((ext_vector_type(8))) short short8;
typedef __attribute__((ext_vector_type(4))) float floatx4;
typedef __attribute__((ext_vector_type(16))) float f32x16;
typedef unsigned short u16;

__device__ __forceinline__ u16 f2bf(float f) {
    union { float f; uint32_t u; } v; v.f = f;
    return (u16)((v.u + 0x7fffu + ((v.u >> 16) & 1u)) >> 16);
}

__device__ __forceinline__ uint32_t cvt_pk_bf16(float lo, float hi) {
    uint32_t r;
    asm("v_cvt_pk_bf16_f32 %0, %1, %2" : "=v"(r) : "v"(lo), "v"(hi));
    return r;
}

// swaps a.hi-half with b.lo-half. NOTE (R10-R12): only safe with two GENUINELY
// DISTINCT values (PV_SUB). Self-join failed twice — use __shfl_xor for that.
__device__ __forceinline__ void pl32swap(uint32_t &a, uint32_t &b) {
    asm("v_permlane32_swap_b32 %0, %1" : "+v"(a), "+v"(b));
}

// raw v_exp_f32: computes 2^x
__device__ __forceinline__ float exp2f_fast(float x) {
    float r; asm("v_exp_f32 %0, %1" : "=v"(r) : "v"(x)); return r;
}

__device__ __forceinline__ float m3f(float a, float b, float c) {
    return fmaxf(fmaxf(a, b), c);   // clang fuses to v_max3_f32
}

__device__ __forceinline__ float vmax16(const f32x16& v) {
    float a0 = m3f(v[0], v[1], v[2]);
    float a1 = m3f(v[3], v[4], v[5]);
    float a2 = m3f(v[6], v[7], v[8]);
    float a3 = m3f(v[9], v[10], v[11]);
    float a4 = m3f(v[12], v[13], v[14]);
    return fmaxf(m3f(a0, a1, v[15]), m3f(a2, a3, a4));
}

__device__ __forceinline__ f32x16 zero16() {
    f32x16 z;
    #pragma unroll
    for (int i = 0; i < 16; i++) z[i] = 0.f;
    return z;
}

#define GLDS(gsrc, ldst) __builtin_amdgcn_global_load_lds( \
    (const __attribute__((address_space(1))) void*)(gsrc), \
    (__attribute__((address_space(3))) void*)(ldst), 16, 0, 0)

// ---------------- fp32 -> bf16 convert, all three tensors in one launch ----------------
__global__ __launch_bounds__(256) void cvt_all(const float* __restrict__ x,
                                               const float* __restrict__ w1,
                                               const float* __restrict__ w2,
                                               u16* __restrict__ xb,
                                               u16* __restrict__ w1b,
                                               u16* __restrict__ w2b) {
    int i = blockIdx.x * 256 + threadIdx.x;
    const float4* src; ushort4* dst; int j;
    if (i < 1048576)      { src = (const float4*)x;  dst = (ushort4*)xb;  j = i; }
    else if (i < 1835008) { src = (const float4*)w1; dst = (ushort4*)w1b; j = i - 1048576; }
    else                  { src = (const float4*)w2; dst = (ushort4*)w2b; j = i - 1835008; }
    float4 f = src[j];
    ushort4 o;
    o.x = f2bf(f.x); o.y = f2bf(f.y); o.z = f2bf(f.z); o.w = f2bf(f.w);
    dst[j] = o;
}

// ---------------- double-buffered 128x128 GEMM mainloop (qkv, best measured): C = A * B^T ----
// Final verdict across 5 variants: dbuf-128²/BK32 (49.5us) > tri-buf (55.4) ≈
// 4-phase-256² (54.7, R14: 1 blk/CU lockstep) < BK64 (73.5). Do not revisit.
__device__ __forceinline__ void gemm128_dbuf(const u16* __restrict__ A,
                                             const u16* __restrict__ B,
                                             int mbase, int nbase, int K,
                                             u16* Alds, u16* Blds,
                                             floatx4 acc[4][4]) {
    const int tid = threadIdx.x;
    const int lane = tid & 63;
    const int l15 = lane & 15, quad = lane >> 4;
    const int wave = tid >> 6;
    const int wr = wave >> 1, wc = wave & 1;
    #pragma unroll
    for (int i = 0; i < 4; i++)
        #pragma unroll
        for (int j = 0; j < 4; j++)
            acc[i][j] = (floatx4){0.f, 0.f, 0.f, 0.f};

    const int r0 = tid >> 2, kg0 = (tid & 3) * 8;
    const u16* Arow0 = A + (size_t)(mbase + r0) * K + kg0;
    const u16* Arow1 = A + (size_t)(mbase + r0 + 64) * K + kg0;
    const u16* Brow0 = B + (size_t)(nbase + r0) * K + kg0;
    const u16* Brow1 = B + (size_t)(nbase + r0 + 64) * K + kg0;

    GLDS(Arow0, Alds + tid * 8);
    GLDS(Arow1, Alds + (256 + tid) * 8);
    GLDS(Brow0, Blds + tid * 8);
    GLDS(Brow1, Blds + (256 + tid) * 8);
    __syncthreads();

    const int NT = K >> 5;
    for (int t = 0; t < NT; t++) {
        const int cur = t & 1;
        if (t + 1 < NT) {
            const int k0 = (t + 1) << 5;
            u16* Ad = Alds + (cur ^ 1) * 4096;
            u16* Bd = Blds + (cur ^ 1) * 4096;
            GLDS(Arow0 + k0, Ad + tid * 8);
            GLDS(Arow1 + k0, Ad + (256 + tid) * 8);
            GLDS(Brow0 + k0, Bd + tid * 8);
            GLDS(Brow1 + k0, Bd + (256 + tid) * 8);
        }
        const u16* Ac = Alds + cur * 4096;
        const u16* Bc = Blds + cur * 4096;
        short8 af[4], bf[4];
        #pragma unroll
        for (int i = 0; i < 4; i++)
            af[i] = *(const short8*)(Ac + (wr * 64 + i * 16 + l15) * 32 + quad * 8);
        #pragma unroll
        for (int j = 0; j < 4; j++)
            bf[j] = *(const short8*)(Bc + (wc * 64 + j * 16 + l15) * 32 + quad * 8);
        #pragma unroll
        for (int i = 0; i < 4; i++)
            #pragma unroll
            for (int j = 0; j < 4; j++)
                acc[i][j] = __builtin_amdgcn_mfma_f32_16x16x32_bf16(af[i], bf[j], acc[i][j], 0, 0, 0);
        __syncthreads();   // drains vmcnt (tile t+1 staged) + WAR guard
    }
}

// ---------------- double-buffered 128Mx64N GEMM mainloop (proj): C = A * B^T ----------------
__device__ __forceinline__ void gemm128x64_dbuf(const u16* __restrict__ A,
                                                const u16* __restrict__ B,
                                                int mbase, int nbase, int K,
                                                u16* Alds, u16* Blds,
                                                floatx4 acc[4][2]) {
    const int tid = threadIdx.x;
    const int lane = tid & 63;
    const int l15 = lane & 15, quad = lane >> 4;
    const int wave = tid >> 6;
    const int wr = wave >> 1, wc = wave & 1;
    #pragma unroll
    for (int i = 0; i < 4; i++)
        #pragma unroll
        for (int j = 0; j < 2; j++)
            acc[i][j] = (floatx4){0.f, 0.f, 0.f, 0.f};

    const int r0 = tid >> 2, kg0 = (tid & 3) * 8;
    const u16* Arow0 = A + (size_t)(mbase + r0) * K + kg0;
    const u16* Arow1 = A + (size_t)(mbase + r0 + 64) * K + kg0;
    const u16* Brow0 = B + (size_t)(nbase + r0) * K + kg0;

    GLDS(Arow0, Alds + tid * 8);
    GLDS(Arow1, Alds + (256 + tid) * 8);
    GLDS(Brow0, Blds + tid * 8);
    __syncthreads();

    const int NT = K >> 5;
    for (int t = 0; t < NT; t++) {
        const int cur = t & 1;
        if (t + 1 < NT) {
            const int k0 = (t + 1) << 5;
            u16* Ad = Alds + (cur ^ 1) * 4096;
            u16* Bd = Blds + (cur ^ 1) * 2048;
            GLDS(Arow0 + k0, Ad + tid * 8);
            GLDS(Arow1 + k0, Ad + (256 + tid) * 8);
            GLDS(Brow0 + k0, Bd + tid * 8);
        }
        const u16* Ac = Alds + cur * 4096;
        const u16* Bc = Blds + cur * 2048;
        short8 af[4], bf[2];
        #pragma unroll
        for (int i = 0; i < 4; i++)
            af[i] = *(const short8*)(Ac + (wr * 64 + i * 16 + l15) * 32 + quad * 8);
        #pragma unroll
        for (int j = 0; j < 2; j++)
            bf[j] = *(const short8*)(Bc + (wc * 32 + j * 16 + l15) * 32 + quad * 8);
        #pragma unroll
        for (int i = 0; i < 4; i++)
            #pragma unroll
            for (int j = 0; j < 2; j++)
                acc[i][j] = __builtin_amdgcn_mfma_f32_16x16x32_bf16(af[i], bf[j], acc[i][j], 0, 0, 0);
        __syncthreads();   // drains vmcnt (tile t+1 staged) + WAR guard
    }
}

// ---------------- QKV GEMM: [4096,1024] x [3072,1024]^T + bias ----------------
__global__ __launch_bounds__(256) void qkv_gemm(const u16* __restrict__ xb,
                                                const u16* __restrict__ wb,
                                                const float* __restrict__ bias,
                                                u16* __restrict__ Qo, u16* __restrict__ Ko,
                                                u16* __restrict__ Vt) {
    __shared__ __align__(16) u16 Alds[2 * 128 * 32];
    __shared__ __align__(16) u16 Blds[2 * 128 * 32];
    const int mbase = blockIdx.y * 128;
    const int nbase = blockIdx.x * 128;
    floatx4 acc[4][4];
    gemm128_dbuf(xb, wb, mbase, nbase, 1024, Alds, Blds, acc);
    const int lane = threadIdx.x & 63;
    const int wave = threadIdx.x >> 6;
    const int wr = wave >> 1, wc = wave & 1;
    const int l15 = lane & 15, quad = lane >> 4;
    const int which = nbase >> 10;   // uniform per block (nbase multiple of 128)
    #pragma unroll
    for (int j = 0; j < 4; j++) {
        int n = nbase + wc * 64 + j * 16 + l15;
        float bv = bias[n];
        int within = n & 1023;
        int h = within >> 6, d = within & 63;
        #pragma unroll
        for (int i = 0; i < 4; i++) {
            int m0 = mbase + wr * 64 + i * 16 + quad * 4;
            int b = m0 >> 11;
            int bh = b * NHEADS + h;
            if (which == 2) {
                // V fragment-major: for fixed (i,j), r=0..3 are 4 consecutive u16
                int l0 = m0 & 2047;
                int slot = ((l0 >> 5) & 1) * 256 + ((l0 >> 4) & 1) * 128 + (d >> 5) * 64 + ((l0 >> 3) & 1) * 32 + (d & 31);
                ushort4 pk;
                pk.x = f2bf(acc[i][j][0] + bv); pk.y = f2bf(acc[i][j][1] + bv);
                pk.z = f2bf(acc[i][j][2] + bv); pk.w = f2bf(acc[i][j][3] + bv);
                *(ushort4*)(Vt + (size_t)bh * (SL * HD) + (size_t)(l0 >> 6) * 4096 + slot * 8 + (l0 & 7)) = pk;
            } else {
                #pragma unroll
                for (int r = 0; r < 4; r++) {
                    int m = m0 + r;
                    int l = m & 2047;
                    float v = acc[i][j][r] + bv;
                    if (which == 0) {
                        // SCALE * log2(e) folded -> flash works in exp2 domain
                        Qo[((size_t)bh * SL + l) * HD + d] = f2bf(v * 0.18033688f);
                    } else {
                        int slot = ((l >> 5) & 1) * 256 + (d >> 4) * 64 + ((d >> 3) & 1) * 32 + (l & 31);
                        Ko[(size_t)bh * (SL * HD) + (size_t)(l >> 6) * 4096 + slot * 8 + (d & 7)] = f2bf(v);
                    }
                }
            }
        }
    }
}

// ---------------- Flash attention v9: KV-split + V read DIRECT from L2 ----------------
// v9: V staging deleted (Common-mistake #7 / m169: staging L2-resident data is
// pure overhead). V is fragment-major in global, so PV reads are coalesced
// global_load_dwordx4 at base+lane*16 with NO softmax dependency (hoistable).
// LDS 64 KB -> 36 KB => 2 -> 4 blocks/CU (wave-capped max), doubling the TLP
// that hides the serial softmax chain. K staging + deferred l_i join unchanged.
__global__ __launch_bounds__(512, 4) void flash_kernel(const u16* __restrict__ Q,
                                                       const u16* __restrict__ K,
                                                       const u16* __restrict__ V,
                                                       u16* __restrict__ AO) {
    // 36864 B: K dbuf 2 halves x 16 KB = 32 KB; combine scratch needs 35840 B
    __shared__ __align__(16) u16 smem[18432];
    const int tid = threadIdx.x;
    const int lane = tid & 63;
    const int wave = tid >> 6;          // 0..7
    const int qc = wave & 3;            // q-chunk within block
    const int kvh = wave >> 2;          // KV half
    const int tl = tid & 255;           // thread index within half-group
    const int hi = lane >> 5;
    const int l31 = lane & 31;
    const int lane8 = lane * 8;

    const int bid = (int)blockIdx.x;
    const int swz = (bid & 7) * 64 + (bid >> 3);
    const int bh = swz >> 4;
    const int qb = swz & 15;
    const int b = bh >> 4, hd = bh & 15;
    const int qbase = qb * 128 + qc * 32;

    const u16* Qp = Q + (size_t)bh * SL * HD;
    const u16* Kg = K + (size_t)bh * (SL * HD) + (size_t)kvh * 16 * 4096;
    const u16* Vg = V + (size_t)bh * (SL * HD) + (size_t)kvh * 16 * 4096;

    u16* Kb_ = smem + kvh * 8192;       // per-half K double-buffer (2 x 4096 u16)

    short8 qf[4];
    #pragma unroll
    for (int c = 0; c < 4; c++)
        qf[c] = *(const short8*)(Qp + (size_t)(qbase + l31) * HD + c * 16 + hi * 8);

    f32x16 accO0 = zero16(), accO1 = zero16();
    float m_i = -__builtin_inff();
    float l_i = 0.f;    // per-lane HALF-row partial; joined once after the loop

    GLDS(Kg + tl * 8,         Kb_ + tl * 8);
    GLDS(Kg + (256 + tl) * 8, Kb_ + (256 + tl) * 8);
    __syncthreads();

    union PW { uint32_t w[4]; short8 s8; };

    #pragma unroll 1
    for (int t = 0; t < 16; t++) {
        const int cur = t & 1;
        if (t + 1 < 16) {
            const u16* ks = Kg + (size_t)(t + 1) * 4096;
            u16* kd = Kb_ + (cur ^ 1) * 4096;
            GLDS(ks + tl * 8,         kd + tl * 8);
            GLDS(ks + (256 + tl) * 8, kd + (256 + tl) * 8);
        }
        const u16* Kt  = Kb_ + cur * 4096;
        const u16* Vt_ = Vg + (size_t)t * 4096;    // GLOBAL (L2-resident), fragment-major

        f32x16 sA = zero16(), sB = zero16();
        __builtin_amdgcn_s_setprio(1);
        #pragma unroll
        for (int c = 0; c < 4; c++) {
            short8 kf = *(const short8*)(Kt + c * 512 + lane8);
            sA = __builtin_amdgcn_mfma_f32_32x32x16_bf16(kf, qf[c], sA, 0, 0, 0);
        }
        #pragma unroll
        for (int c = 0; c < 4; c++) {
            short8 kf = *(const short8*)(Kt + 2048 + c * 512 + lane8);
            sB = __builtin_amdgcn_mfma_f32_32x32x16_bf16(kf, qf[c], sB, 0, 0, 0);
        }
        __builtin_amdgcn_s_setprio(0);

        float pmax = fmaxf(vmax16(sA), vmax16(sB));
        if (!__all(pmax - m_i <= 24.0f)) {
            float mo = m_i;
            float mn = fmaxf(mo, fmaxf(pmax, __shfl_xor(pmax, 32, 64)));  // pair-consistent m
            m_i = mn;
            float alpha = exp2f_fast(mo - mn);
            l_i *= alpha;
            #pragma unroll
            for (int e = 0; e < 16; e++) { accO0[e] *= alpha; accO1[e] *= alpha; }
        }
        #pragma unroll
        for (int e = 0; e < 16; e++) sA[e] = exp2f_fast(sA[e] - m_i);
        #pragma unroll
        for (int e = 0; e < 16; e++) sB[e] = exp2f_fast(sB[e] - m_i);
        float r0 = 0.f, r1 = 0.f, r2 = 0.f, r3 = 0.f;
        #pragma unroll
        for (int e = 0; e < 16; e += 4) {
            r0 += sA[e]; r1 += sA[e + 1]; r2 += sA[e + 2]; r3 += sA[e + 3];
        }
        #pragma unroll
        for (int e = 0; e < 16; e += 4) {
            r0 += sB[e]; r1 += sB[e + 1]; r2 += sB[e + 2]; r3 += sB[e + 3];
        }
        l_i += (r0 + r1) + (r2 + r3);   // half-row partial; deferred join (v8)

#define PV_SUB(SV, OFF) { \
        uint32_t a0 = cvt_pk_bf16(SV[0], SV[1]);  uint32_t b0 = cvt_pk_bf16(SV[4], SV[5]);  pl32swap(a0, b0); \
        uint32_t a1 = cvt_pk_bf16(SV[2], SV[3]);  uint32_t b1 = cvt_pk_bf16(SV[6], SV[7]);  pl32swap(a1, b1); \
        PW f0; f0.w[0] = a0; f0.w[1] = a1; f0.w[2] = b0; f0.w[3] = b1; \
        accO0 = __builtin_amdgcn_mfma_f32_32x32x16_bf16(*(const short8*)(Vt_ + (OFF) + lane8),        f0.s8, accO0, 0, 0, 0); \
        accO1 = __builtin_amdgcn_mfma_f32_32x32x16_bf16(*(const short8*)(Vt_ + (OFF) + 512 + lane8),  f0.s8, accO1, 0, 0, 0); \
        uint32_t c0 = cvt_pk_bf16(SV[8], SV[9]);  uint32_t d0 = cvt_pk_bf16(SV[12], SV[13]); pl32swap(c0, d0); \
        uint32_t c1 = cvt_pk_bf16(SV[10], SV[11]); uint32_t d1 = cvt_pk_bf16(SV[14], SV[15]); pl32swap(c1, d1); \
        PW f1; f1.w[0] = c0; f1.w[1] = c1; f1.w[2] = d0; f1.w[3] = d1; \
        accO0 = __builtin_amdgcn_mfma_f32_32x32x16_bf16(*(const short8*)(Vt_ + (OFF) + 1024 + lane8),       f1.s8, accO0, 0, 0, 0); \
        accO1 = __builtin_amdgcn_mfma_f32_32x32x16_bf16(*(const short8*)(Vt_ + (OFF) + 1024 + 512 + lane8), f1.s8, accO1, 0, 0, 0); }

        __builtin_amdgcn_s_setprio(1);
        PV_SUB(sA, 0);
        PV_SUB(sB, 2048);
        __builtin_amdgcn_s_setprio(0);
#undef PV_SUB

        __syncthreads();   // drains vmcnt (next K tile staged) + WAR guard
    }

    // ---- one-time lane-pair join of the deferred l_i partials (v8) ----
    l_i += __shfl_xor(l_i, 32, 64);

    // ---- cross-half combine through (now dead) staging LDS ----
    float* xch = (float*)smem;
    if (kvh) {
        float* p = xch + (qc * 64 + lane) * 35;
        #pragma unroll
        for (int e = 0; e < 16; e++) { p[e] = accO0[e]; p[16 + e] = accO1[e]; }
        p[32] = m_i; p[33] = l_i;
    }
    __syncthreads();
    if (!kvh) {
        const float* p = xch + (qc * 64 + lane) * 35;
        float mB = p[32], lB = p[33];
        float m = fmaxf(m_i, mB);
        float s0 = exp2f_fast(m_i - m);
        float s1 = exp2f_fast(mB - m);
        float inv = 1.f / (s0 * l_i + s1 * lB);
        const size_t rowbase = ((size_t)(b * SL + qbase + l31)) * D_MODEL + hd * HD;
        #pragma unroll
        for (int rg = 0; rg < 4; rg++) {
            ushort4 o0, o1;
            o0.x = f2bf((s0 * accO0[rg * 4 + 0] + s1 * p[rg * 4 + 0]) * inv);
            o0.y = f2bf((s0 * accO0[rg * 4 + 1] + s1 * p[rg * 4 + 1]) * inv);
            o0.z = f2bf((s0 * accO0[rg * 4 + 2] + s1 * p[rg * 4 + 2]) * inv);
            o0.w = f2bf((s0 * accO0[rg * 4 + 3] + s1 * p[rg * 4 + 3]) * inv);
            *(ushort4*)(AO + rowbase + rg * 8 + 4 * hi) = o0;
            o1.x = f2bf((s0 * accO1[rg * 4 + 0] + s1 * p[16 + rg * 4 + 0]) * inv);
            o1.y = f2bf((s0 * accO1[rg * 4 + 1] + s1 * p[16 + rg * 4 + 1]) * inv);
            o1.z = f2bf((s0 * accO1[rg * 4 + 2] + s1 * p[16 + rg * 4 + 2]) * inv);
            o1.w = f2bf((s0 * accO1[rg * 4 + 3] + s1 * p[16 + rg * 4 + 3]) * inv);
            *(ushort4*)(AO + rowbase + 32 + rg * 8 + 4 * hi) = o1;
        }
    }
}

// ---------------- Output projection: [4096,1024] x [1024,1024]^T + bias -> fp32 ----------------
__global__ __launch_bounds__(256) void proj_gemm(const u16* __restrict__ ab,
                                                 const u16* __restrict__ wb,
                                                 const float* __restrict__ bias,
                                                 float* __restrict__ out) {
    __shared__ __align__(16) u16 Alds[2 * 4096];
    __shared__ __align__(16) u16 Blds[2 * 2048];
    const int mbase = blockIdx.y * 128;
    const int nbase = blockIdx.x * 64;
    floatx4 acc[4][2];
    gemm128x64_dbuf(ab, wb, mbase, nbase, 1024, Alds, Blds, acc);
    const int lane = threadIdx.x & 63;
    const int wave = threadIdx.x >> 6;
    const int wr = wave >> 1, wc = wave & 1;
    const int l15 = lane & 15, quad = lane >> 4;
    #pragma unroll
    for (int j = 0; j < 2; j++) {
        int n = nbase + wc * 32 + j * 16 + l15;
        float bv = bias[n];
        #pragma unroll
        for (int i = 0; i < 4; i++) {
            #pragma unroll
            for (int r = 0; r < 4; r++) {
                int m = mbase + wr * 64 + i * 16 + quad * 4 + r;
                out[(size_t)m * D_MODEL + n] = acc[i][j][r] + bv;
            }
        }
    }
}

extern "C" void kernel_launch(void* const* d_in, const int* in_sizes, int n_in,
                              void* d_out, int out_size, void* d_ws, size_t ws_size,
                              hipStream_t stream) {
    const float* x      = (const float*)d_in[0];
    const float* qkv_w  = (const float*)d_in[1];
    const float* qkv_b  = (const float*)d_in[2];
    const float* proj_w = (const float*)d_in[3];
    const float* proj_b = (const float*)d_in[4];
    float* out = (float*)d_out;
    char* ws = (char*)d_ws;

    u16* xb    = (u16*)(ws);             // x bf16        [4096,1024]   8 MB
    u16* wqkv  = (u16*)(ws + 8388608);   // qkv_w bf16    [3072,1024]   6 MB
    u16* wproj = (u16*)(ws + 14680064);  // proj_w bf16   [1024,1024]   2 MB
    u16* Qb    = (u16*)(ws + 16777216);  // Q bf16 (pre-scaled, exp2 domain) 8 MB
    u16* Kb    = (u16*)(ws + 25165824);  // K bf16 fragment-major 8 MB
    u16* Vt    = (u16*)(ws + 33554432);  // V bf16 fragment-major 8 MB
    u16* AO    = (u16*)(ws);             // attn out bf16 ALIASES xb (lifetimes disjoint)

    cvt_all<<<8192, 256, 0, stream>>>(x, qkv_w, proj_w, xb, wqkv, wproj);
    qkv_gemm<<<dim3(NQKV / 128, SEQ / 128), 256, 0, stream>>>(xb, wqkv, qkv_b, Qb, Kb, Vt);
    flash_kernel<<<dim3(512), 512, 0, stream>>>(Qb, Kb, Vt, AO);
    proj_gemm<<<dim3(D_MODEL / 64, SEQ / 128), 256, 0, stream>>>(AO, wproj, proj_b, out);
}

// Round 17
// 187.709 us; speedup vs baseline: 1.0470x; 1.0334x over previous
//
#include <hip/hip_runtime.h>
#include <hip/hip_bf16.h>
#include <cstdint>
#include <cstddef>

#define D_MODEL 1024
#define NHEADS 16
#define HD 64
#define NB 2
#define SL 2048
#define SEQ (NB*SL)      // 4096
#define NQKV (3*D_MODEL) // 3072

typedef __attribute__((ext_vector_type(8))) short short8;
typedef __attribute__((ext_vector_type(4))) float floatx4;
typedef __attribute__((ext_vector_type(16))) float f32x16;
typedef unsigned short u16;

__device__ __forceinline__ u16 f2bf(float f) {
    union { float f; uint32_t u; } v; v.f = f;
    return (u16)((v.u + 0x7fffu + ((v.u >> 16) & 1u)) >> 16);
}

__device__ __forceinline__ uint32_t cvt_pk_bf16(float lo, float hi) {
    uint32_t r;
    asm("v_cvt_pk_bf16_f32 %0, %1, %2" : "=v"(r) : "v"(lo), "v"(hi));
    return r;
}

// swaps a.hi-half with b.lo-half. NOTE (R10-R12): only safe with two GENUINELY
// DISTINCT values (PV_SUB). Self-join failed twice — use __shfl_xor for that.
__device__ __forceinline__ void pl32swap(uint32_t &a, uint32_t &b) {
    asm("v_permlane32_swap_b32 %0, %1" : "+v"(a), "+v"(b));
}

// raw v_exp_f32: computes 2^x
__device__ __forceinline__ float exp2f_fast(float x) {
    float r; asm("v_exp_f32 %0, %1" : "=v"(r) : "v"(x)); return r;
}

__device__ __forceinline__ float m3f(float a, float b, float c) {
    return fmaxf(fmaxf(a, b), c);   // clang fuses to v_max3_f32
}

__device__ __forceinline__ float vmax16(const f32x16& v) {
    float a0 = m3f(v[0], v[1], v[2]);
    float a1 = m3f(v[3], v[4], v[5]);
    float a2 = m3f(v[6], v[7], v[8]);
    float a3 = m3f(v[9], v[10], v[11]);
    float a4 = m3f(v[12], v[13], v[14]);
    return fmaxf(m3f(a0, a1, v[15]), m3f(a2, a3, a4));
}

__device__ __forceinline__ f32x16 zero16() {
    f32x16 z;
    #pragma unroll
    for (int i = 0; i < 16; i++) z[i] = 0.f;
    return z;
}

#define GLDS(gsrc, ldst) __builtin_amdgcn_global_load_lds( \
    (const __attribute__((address_space(1))) void*)(gsrc), \
    (__attribute__((address_space(3))) void*)(ldst), 16, 0, 0)

// ---------------- fp32 -> bf16 convert, all three tensors in one launch ----------------
__global__ __launch_bounds__(256) void cvt_all(const float* __restrict__ x,
                                               const float* __restrict__ w1,
                                               const float* __restrict__ w2,
                                               u16* __restrict__ xb,
                                               u16* __restrict__ w1b,
                                               u16* __restrict__ w2b) {
    int i = blockIdx.x * 256 + threadIdx.x;
    const float4* src; ushort4* dst; int j;
    if (i < 1048576)      { src = (const float4*)x;  dst = (ushort4*)xb;  j = i; }
    else if (i < 1835008) { src = (const float4*)w1; dst = (ushort4*)w1b; j = i - 1048576; }
    else                  { src = (const float4*)w2; dst = (ushort4*)w2b; j = i - 1835008; }
    float4 f = src[j];
    ushort4 o;
    o.x = f2bf(f.x); o.y = f2bf(f.y); o.z = f2bf(f.z); o.w = f2bf(f.w);
    dst[j] = o;
}

// ---------------- double-buffered 128x128 GEMM mainloop (qkv, best measured): C = A * B^T ----
// Final verdict across 5 variants: dbuf-128²/BK32 (49.5us) > tri-buf (55.4) ≈
// 4-phase-256² (54.7, R14: 1 blk/CU lockstep) < BK64 (73.5). Do not revisit.
__device__ __forceinline__ void gemm128_dbuf(const u16* __restrict__ A,
                                             const u16* __restrict__ B,
                                             int mbase, int nbase, int K,
                                             u16* Alds, u16* Blds,
                                             floatx4 acc[4][4]) {
    const int tid = threadIdx.x;
    const int lane = tid & 63;
    const int l15 = lane & 15, quad = lane >> 4;
    const int wave = tid >> 6;
    const int wr = wave >> 1, wc = wave & 1;
    #pragma unroll
    for (int i = 0; i < 4; i++)
        #pragma unroll
        for (int j = 0; j < 4; j++)
            acc[i][j] = (floatx4){0.f, 0.f, 0.f, 0.f};

    const int r0 = tid >> 2, kg0 = (tid & 3) * 8;
    const u16* Arow0 = A + (size_t)(mbase + r0) * K + kg0;
    const u16* Arow1 = A + (size_t)(mbase + r0 + 64) * K + kg0;
    const u16* Brow0 = B + (size_t)(nbase + r0) * K + kg0;
    const u16* Brow1 = B + (size_t)(nbase + r0 + 64) * K + kg0;

    GLDS(Arow0, Alds + tid * 8);
    GLDS(Arow1, Alds + (256 + tid) * 8);
    GLDS(Brow0, Blds + tid * 8);
    GLDS(Brow1, Blds + (256 + tid) * 8);
    __syncthreads();

    const int NT = K >> 5;
    for (int t = 0; t < NT; t++) {
        const int cur = t & 1;
        if (t + 1 < NT) {
            const int k0 = (t + 1) << 5;
            u16* Ad = Alds + (cur ^ 1) * 4096;
            u16* Bd = Blds + (cur ^ 1) * 4096;
            GLDS(Arow0 + k0, Ad + tid * 8);
            GLDS(Arow1 + k0, Ad + (256 + tid) * 8);
            GLDS(Brow0 + k0, Bd + tid * 8);
            GLDS(Brow1 + k0, Bd + (256 + tid) * 8);
        }
        const u16* Ac = Alds + cur * 4096;
        const u16* Bc = Blds + cur * 4096;
        short8 af[4], bf[4];
        #pragma unroll
        for (int i = 0; i < 4; i++)
            af[i] = *(const short8*)(Ac + (wr * 64 + i * 16 + l15) * 32 + quad * 8);
        #pragma unroll
        for (int j = 0; j < 4; j++)
            bf[j] = *(const short8*)(Bc + (wc * 64 + j * 16 + l15) * 32 + quad * 8);
        #pragma unroll
        for (int i = 0; i < 4; i++)
            #pragma unroll
            for (int j = 0; j < 4; j++)
                acc[i][j] = __builtin_amdgcn_mfma_f32_16x16x32_bf16(af[i], bf[j], acc[i][j], 0, 0, 0);
        __syncthreads();   // drains vmcnt (tile t+1 staged) + WAR guard
    }
}

// ---------------- double-buffered 128Mx64N GEMM mainloop (proj): C = A * B^T ----------------
__device__ __forceinline__ void gemm128x64_dbuf(const u16* __restrict__ A,
                                                const u16* __restrict__ B,
                                                int mbase, int nbase, int K,
                                                u16* Alds, u16* Blds,
                                                floatx4 acc[4][2]) {
    const int tid = threadIdx.x;
    const int lane = tid & 63;
    const int l15 = lane & 15, quad = lane >> 4;
    const int wave = tid >> 6;
    const int wr = wave >> 1, wc = wave & 1;
    #pragma unroll
    for (int i = 0; i < 4; i++)
        #pragma unroll
        for (int j = 0; j < 2; j++)
            acc[i][j] = (floatx4){0.f, 0.f, 0.f, 0.f};

    const int r0 = tid >> 2, kg0 = (tid & 3) * 8;
    const u16* Arow0 = A + (size_t)(mbase + r0) * K + kg0;
    const u16* Arow1 = A + (size_t)(mbase + r0 + 64) * K + kg0;
    const u16* Brow0 = B + (size_t)(nbase + r0) * K + kg0;

    GLDS(Arow0, Alds + tid * 8);
    GLDS(Arow1, Alds + (256 + tid) * 8);
    GLDS(Brow0, Blds + tid * 8);
    __syncthreads();

    const int NT = K >> 5;
    for (int t = 0; t < NT; t++) {
        const int cur = t & 1;
        if (t + 1 < NT) {
            const int k0 = (t + 1) << 5;
            u16* Ad = Alds + (cur ^ 1) * 4096;
            u16* Bd = Blds + (cur ^ 1) * 2048;
            GLDS(Arow0 + k0, Ad + tid * 8);
            GLDS(Arow1 + k0, Ad + (256 + tid) * 8);
            GLDS(Brow0 + k0, Bd + tid * 8);
        }
        const u16* Ac = Alds + cur * 4096;
        const u16* Bc = Blds + cur * 2048;
        short8 af[4], bf[2];
        #pragma unroll
        for (int i = 0; i < 4; i++)
            af[i] = *(const short8*)(Ac + (wr * 64 + i * 16 + l15) * 32 + quad * 8);
        #pragma unroll
        for (int j = 0; j < 2; j++)
            bf[j] = *(const short8*)(Bc + (wc * 32 + j * 16 + l15) * 32 + quad * 8);
        #pragma unroll
        for (int i = 0; i < 4; i++)
            #pragma unroll
            for (int j = 0; j < 2; j++)
                acc[i][j] = __builtin_amdgcn_mfma_f32_16x16x32_bf16(af[i], bf[j], acc[i][j], 0, 0, 0);
        __syncthreads();   // drains vmcnt (tile t+1 staged) + WAR guard
    }
}

// ---------------- QKV GEMM: [4096,1024] x [3072,1024]^T + bias ----------------
__global__ __launch_bounds__(256) void qkv_gemm(const u16* __restrict__ xb,
                                                const u16* __restrict__ wb,
                                                const float* __restrict__ bias,
                                                u16* __restrict__ Qo, u16* __restrict__ Ko,
                                                u16* __restrict__ Vt) {
    __shared__ __align__(16) u16 Alds[2 * 128 * 32];
    __shared__ __align__(16) u16 Blds[2 * 128 * 32];
    const int mbase = blockIdx.y * 128;
    const int nbase = blockIdx.x * 128;
    floatx4 acc[4][4];
    gemm128_dbuf(xb, wb, mbase, nbase, 1024, Alds, Blds, acc);
    const int lane = threadIdx.x & 63;
    const int wave = threadIdx.x >> 6;
    const int wr = wave >> 1, wc = wave & 1;
    const int l15 = lane & 15, quad = lane >> 4;
    const int which = nbase >> 10;   // uniform per block (nbase multiple of 128)
    #pragma unroll
    for (int j = 0; j < 4; j++) {
        int n = nbase + wc * 64 + j * 16 + l15;
        float bv = bias[n];
        int within = n & 1023;
        int h = within >> 6, d = within & 63;
        #pragma unroll
        for (int i = 0; i < 4; i++) {
            int m0 = mbase + wr * 64 + i * 16 + quad * 4;
            int b = m0 >> 11;
            int bh = b * NHEADS + h;
            if (which == 2) {
                // V fragment-major: for fixed (i,j), r=0..3 are 4 consecutive u16
                int l0 = m0 & 2047;
                int slot = ((l0 >> 5) & 1) * 256 + ((l0 >> 4) & 1) * 128 + (d >> 5) * 64 + ((l0 >> 3) & 1) * 32 + (d & 31);
                ushort4 pk;
                pk.x = f2bf(acc[i][j][0] + bv); pk.y = f2bf(acc[i][j][1] + bv);
                pk.z = f2bf(acc[i][j][2] + bv); pk.w = f2bf(acc[i][j][3] + bv);
                *(ushort4*)(Vt + (size_t)bh * (SL * HD) + (size_t)(l0 >> 6) * 4096 + slot * 8 + (l0 & 7)) = pk;
            } else {
                #pragma unroll
                for (int r = 0; r < 4; r++) {
                    int m = m0 + r;
                    int l = m & 2047;
                    float v = acc[i][j][r] + bv;
                    if (which == 0) {
                        // SCALE * log2(e) folded -> flash works in exp2 domain
                        Qo[((size_t)bh * SL + l) * HD + d] = f2bf(v * 0.18033688f);
                    } else {
                        int slot = ((l >> 5) & 1) * 256 + (d >> 4) * 64 + ((d >> 3) & 1) * 32 + (l & 31);
                        Ko[(size_t)bh * (SL * HD) + (size_t)(l >> 6) * 4096 + slot * 8 + (d & 7)] = f2bf(v);
                    }
                }
            }
        }
    }
}

// ---------------- Flash attention v8: in-block KV-split + DEFERRED l_i join ----------------
// 8 waves / 512 threads: waves 0-3 process keys [0,1024), waves 4-7 [1024,2048)
// for the same 128 q-rows. Each half has its own 32 KB K/V double-buffer.
// v8: the per-tile lane l<->l+32 SUM join is deleted — l_i is kept as a
// per-lane half-row partial (valid because m_i is pair-consistent via the
// guarded max join, and l_i's update is linear in rs) and joined ONCE after
// the loop. (R15 lesson: V-direct-from-L2 regressed — grid caps occupancy at
// 2 blocks/CU, so smaller LDS buys nothing and L2 latency lands on PV path.)
__global__ __launch_bounds__(512, 4) void flash_kernel(const u16* __restrict__ Q,
                                                       const u16* __restrict__ K,
                                                       const u16* __restrict__ V,
                                                       u16* __restrict__ AO) {
    __shared__ __align__(16) u16 smem[32768];   // [half][K dbuf 8192 u16 | V dbuf 8192 u16]
    const int tid = threadIdx.x;
    const int lane = tid & 63;
    const int wave = tid >> 6;          // 0..7
    const int qc = wave & 3;            // q-chunk within block
    const int kvh = wave >> 2;          // KV half
    const int tl = tid & 255;           // thread index within half-group
    const int hi = lane >> 5;
    const int l31 = lane & 31;
    const int lane8 = lane * 8;

    const int bid = (int)blockIdx.x;
    const int swz = (bid & 7) * 64 + (bid >> 3);
    const int bh = swz >> 4;
    const int qb = swz & 15;
    const int b = bh >> 4, hd = bh & 15;
    const int qbase = qb * 128 + qc * 32;

    const u16* Qp = Q + (size_t)bh * SL * HD;
    const u16* Kg = K + (size_t)bh * (SL * HD) + (size_t)kvh * 16 * 4096;
    const u16* Vg = V + (size_t)bh * (SL * HD) + (size_t)kvh * 16 * 4096;

    u16* Kb_ = smem + kvh * 16384;
    u16* Vb_ = smem + kvh * 16384 + 8192;

    short8 qf[4];
    #pragma unroll
    for (int c = 0; c < 4; c++)
        qf[c] = *(const short8*)(Qp + (size_t)(qbase + l31) * HD + c * 16 + hi * 8);

    f32x16 accO0 = zero16(), accO1 = zero16();
    float m_i = -__builtin_inff();
    float l_i = 0.f;    // per-lane HALF-row partial; joined once after the loop

    GLDS(Kg + tl * 8,         Kb_ + tl * 8);
    GLDS(Kg + (256 + tl) * 8, Kb_ + (256 + tl) * 8);
    GLDS(Vg + tl * 8,         Vb_ + tl * 8);
    GLDS(Vg + (256 + tl) * 8, Vb_ + (256 + tl) * 8);
    __syncthreads();

    union PW { uint32_t w[4]; short8 s8; };

    #pragma unroll 1
    for (int t = 0; t < 16; t++) {
        const int cur = t & 1;
        if (t + 1 < 16) {
            const u16* ks = Kg + (size_t)(t + 1) * 4096;
            const u16* vs = Vg + (size_t)(t + 1) * 4096;
            u16* kd = Kb_ + (cur ^ 1) * 4096;
            u16* vd = Vb_ + (cur ^ 1) * 4096;
            GLDS(ks + tl * 8,         kd + tl * 8);
            GLDS(ks + (256 + tl) * 8, kd + (256 + tl) * 8);
            GLDS(vs + tl * 8,         vd + tl * 8);
            GLDS(vs + (256 + tl) * 8, vd + (256 + tl) * 8);
        }
        const u16* Kt  = Kb_ + cur * 4096;
        const u16* Vt_ = Vb_ + cur * 4096;

        f32x16 sA = zero16(), sB = zero16();
        __builtin_amdgcn_s_setprio(1);
        #pragma unroll
        for (int c = 0; c < 4; c++) {
            short8 kf = *(const short8*)(Kt + c * 512 + lane8);
            sA = __builtin_amdgcn_mfma_f32_32x32x16_bf16(kf, qf[c], sA, 0, 0, 0);
        }
        #pragma unroll
        for (int c = 0; c < 4; c++) {
            short8 kf = *(const short8*)(Kt + 2048 + c * 512 + lane8);
            sB = __builtin_amdgcn_mfma_f32_32x32x16_bf16(kf, qf[c], sB, 0, 0, 0);
        }
        __builtin_amdgcn_s_setprio(0);

        float pmax = fmaxf(vmax16(sA), vmax16(sB));
        if (!__all(pmax - m_i <= 24.0f)) {
            float mo = m_i;
            float mn = fmaxf(mo, fmaxf(pmax, __shfl_xor(pmax, 32, 64)));  // pair-consistent m
            m_i = mn;
            float alpha = exp2f_fast(mo - mn);
            l_i *= alpha;
            #pragma unroll
            for (int e = 0; e < 16; e++) { accO0[e] *= alpha; accO1[e] *= alpha; }
        }
        #pragma unroll
        for (int e = 0; e < 16; e++) sA[e] = exp2f_fast(sA[e] - m_i);
        #pragma unroll
        for (int e = 0; e < 16; e++) sB[e] = exp2f_fast(sB[e] - m_i);
        float r0 = 0.f, r1 = 0.f, r2 = 0.f, r3 = 0.f;
        #pragma unroll
        for (int e = 0; e < 16; e += 4) {
            r0 += sA[e]; r1 += sA[e + 1]; r2 += sA[e + 2]; r3 += sA[e + 3];
        }
        #pragma unroll
        for (int e = 0; e < 16; e += 4) {
            r0 += sB[e]; r1 += sB[e + 1]; r2 += sB[e + 2]; r3 += sB[e + 3];
        }
        l_i += (r0 + r1) + (r2 + r3);   // half-row partial; NO per-tile join (v8)

#define PV_SUB(SV, OFF) { \
        uint32_t a0 = cvt_pk_bf16(SV[0], SV[1]);  uint32_t b0 = cvt_pk_bf16(SV[4], SV[5]);  pl32swap(a0, b0); \
        uint32_t a1 = cvt_pk_bf16(SV[2], SV[3]);  uint32_t b1 = cvt_pk_bf16(SV[6], SV[7]);  pl32swap(a1, b1); \
        PW f0; f0.w[0] = a0; f0.w[1] = a1; f0.w[2] = b0; f0.w[3] = b1; \
        accO0 = __builtin_amdgcn_mfma_f32_32x32x16_bf16(*(const short8*)(Vt_ + (OFF) + lane8),        f0.s8, accO0, 0, 0, 0); \
        accO1 = __builtin_amdgcn_mfma_f32_32x32x16_bf16(*(const short8*)(Vt_ + (OFF) + 512 + lane8),  f0.s8, accO1, 0, 0, 0); \
        uint32_t c0 = cvt_pk_bf16(SV[8], SV[9]);  uint32_t d0 = cvt_pk_bf16(SV[12], SV[13]); pl32swap(c0, d0); \
        uint32_t c1 = cvt_pk_bf16(SV[10], SV[11]); uint32_t d1 = cvt_pk_bf16(SV[14], SV[15]); pl32swap(c1, d1); \
        PW f1; f1.w[0] = c0; f1.w[1] = c1; f1.w[2] = d0; f1.w[3] = d1; \
        accO0 = __builtin_amdgcn_mfma_f32_32x32x16_bf16(*(const short8*)(Vt_ + (OFF) + 1024 + lane8),       f1.s8, accO0, 0, 0, 0); \
        accO1 = __builtin_amdgcn_mfma_f32_32x32x16_bf16(*(const short8*)(Vt_ + (OFF) + 1024 + 512 + lane8), f1.s8, accO1, 0, 0, 0); }

        __builtin_amdgcn_s_setprio(1);
        PV_SUB(sA, 0);
        PV_SUB(sB, 2048);
        __builtin_amdgcn_s_setprio(0);
#undef PV_SUB

        __syncthreads();
    }

    // ---- one-time lane-pair join of the deferred l_i partials (v8) ----
    l_i += __shfl_xor(l_i, 32, 64);

    // ---- cross-half combine through (now dead) staging LDS ----
    float* xch = (float*)smem;
    if (kvh) {
        float* p = xch + (qc * 64 + lane) * 35;
        #pragma unroll
        for (int e = 0; e < 16; e++) { p[e] = accO0[e]; p[16 + e] = accO1[e]; }
        p[32] = m_i; p[33] = l_i;
    }
    __syncthreads();
    if (!kvh) {
        const float* p = xch + (qc * 64 + lane) * 35;
        float mB = p[32], lB = p[33];
        float m = fmaxf(m_i, mB);
        float s0 = exp2f_fast(m_i - m);
        float s1 = exp2f_fast(mB - m);
        float inv = 1.f / (s0 * l_i + s1 * lB);
        const size_t rowbase = ((size_t)(b * SL + qbase + l31)) * D_MODEL + hd * HD;
        #pragma unroll
        for (int rg = 0; rg < 4; rg++) {
            ushort4 o0, o1;
            o0.x = f2bf((s0 * accO0[rg * 4 + 0] + s1 * p[rg * 4 + 0]) * inv);
            o0.y = f2bf((s0 * accO0[rg * 4 + 1] + s1 * p[rg * 4 + 1]) * inv);
            o0.z = f2bf((s0 * accO0[rg * 4 + 2] + s1 * p[rg * 4 + 2]) * inv);
            o0.w = f2bf((s0 * accO0[rg * 4 + 3] + s1 * p[rg * 4 + 3]) * inv);
            *(ushort4*)(AO + rowbase + rg * 8 + 4 * hi) = o0;
            o1.x = f2bf((s0 * accO1[rg * 4 + 0] + s1 * p[16 + rg * 4 + 0]) * inv);
            o1.y = f2bf((s0 * accO1[rg * 4 + 1] + s1 * p[16 + rg * 4 + 1]) * inv);
            o1.z = f2bf((s0 * accO1[rg * 4 + 2] + s1 * p[16 + rg * 4 + 2]) * inv);
            o1.w = f2bf((s0 * accO1[rg * 4 + 3] + s1 * p[16 + rg * 4 + 3]) * inv);
            *(ushort4*)(AO + rowbase + 32 + rg * 8 + 4 * hi) = o1;
        }
    }
}

// ---------------- Output projection: [4096,1024] x [1024,1024]^T + bias -> fp32 ----------------
__global__ __launch_bounds__(256) void proj_gemm(const u16* __restrict__ ab,
                                                 const u16* __restrict__ wb,
                                                 const float* __restrict__ bias,
                                                 float* __restrict__ out) {
    __shared__ __align__(16) u16 Alds[2 * 4096];
    __shared__ __align__(16) u16 Blds[2 * 2048];
    const int mbase = blockIdx.y * 128;
    const int nbase = blockIdx.x * 64;
    floatx4 acc[4][2];
    gemm128x64_dbuf(ab, wb, mbase, nbase, 1024, Alds, Blds, acc);
    const int lane = threadIdx.x & 63;
    const int wave = threadIdx.x >> 6;
    const int wr = wave >> 1, wc = wave & 1;
    const int l15 = lane & 15, quad = lane >> 4;
    #pragma unroll
    for (int j = 0; j < 2; j++) {
        int n = nbase + wc * 32 + j * 16 + l15;
        float bv = bias[n];
        #pragma unroll
        for (int i = 0; i < 4; i++) {
            #pragma unroll
            for (int r = 0; r < 4; r++) {
                int m = mbase + wr * 64 + i * 16 + quad * 4 + r;
                out[(size_t)m * D_MODEL + n] = acc[i][j][r] + bv;
            }
        }
    }
}

extern "C" void kernel_launch(void* const* d_in, const int* in_sizes, int n_in,
                              void* d_out, int out_size, void* d_ws, size_t ws_size,
                              hipStream_t stream) {
    const float* x      = (const float*)d_in[0];
    const float* qkv_w  = (const float*)d_in[1];
    const float* qkv_b  = (const float*)d_in[2];
    const float* proj_w = (const float*)d_in[3];
    const float* proj_b = (const float*)d_in[4];
    float* out = (float*)d_out;
    char* ws = (char*)d_ws;

    u16* xb    = (u16*)(ws);             // x bf16        [4096,1024]   8 MB
    u16* wqkv  = (u16*)(ws + 8388608);   // qkv_w bf16    [3072,1024]   6 MB
    u16* wproj = (u16*)(ws + 14680064);  // proj_w bf16   [1024,1024]   2 MB
    u16* Qb    = (u16*)(ws + 16777216);  // Q bf16 (pre-scaled, exp2 domain) 8 MB
    u16* Kb    = (u16*)(ws + 25165824);  // K bf16 fragment-major 8 MB
    u16* Vt    = (u16*)(ws + 33554432);  // V bf16 fragment-major 8 MB
    u16* AO    = (u16*)(ws);             // attn out bf16 ALIASES xb (lifetimes disjoint)

    cvt_all<<<8192, 256, 0, stream>>>(x, qkv_w, proj_w, xb, wqkv, wproj);
    qkv_gemm<<<dim3(NQKV / 128, SEQ / 128), 256, 0, stream>>>(xb, wqkv, qkv_b, Qb, Kb, Vt);
    flash_kernel<<<dim3(512), 512, 0, stream>>>(Qb, Kb, Vt, AO);
    proj_gemm<<<dim3(D_MODEL / 64, SEQ / 128), 256, 0, stream>>>(AO, wproj, proj_b, out);
}